// Round 5
// baseline (369.564 us; speedup 1.0000x reference)
//
#include <hip/hip_runtime.h>

#define NV 300000
#define KT 9
#define NF 64
#define NBLK ((NV + 63) / 64)   // 4688 blocks of 64 rows

typedef __attribute__((ext_vector_type(8))) short bf16x8;
typedef __attribute__((ext_vector_type(4))) float f32x4;
typedef __attribute__((ext_vector_type(4))) float f4;
typedef __attribute__((ext_vector_type(4))) unsigned short u16x4;

// round-to-nearest-even f32 -> bf16 bits
__device__ __forceinline__ unsigned short f2bf(float f) {
    union { float f; unsigned int u; } a; a.f = f;
    unsigned int u = a.u;
    return (unsigned short)((u + 0x7FFFu + ((u >> 16) & 1u)) >> 16);
}

// prep: blocks 0..17 transpose+cvt weights (w[k][f][o] -> wt[k][o][f] bf16),
//       blocks 18..  convert relu(lv) -> bf16 (exact grid, one f4/thread)
__global__ void prep_kernel(const float* __restrict__ lv,
                            const float* __restrict__ w1,
                            const float* __restrict__ w2,
                            unsigned short* __restrict__ xbf0,
                            unsigned short* __restrict__ wt1,
                            unsigned short* __restrict__ wt2) {
    int b = blockIdx.x;
    if (b < 18) {
        const float* w = (b < 9) ? w1 : w2;
        unsigned short* wt = (b < 9) ? wt1 : wt2;
        int k = (b < 9) ? b : b - 9;
        for (int e = threadIdx.x; e < NF * NF; e += 256) {
            int o = e >> 6, f = e & 63;
            wt[(k * NF + o) * NF + f] = f2bf(w[(k * NF + f) * NF + o]);
        }
    } else {
        const int n4 = NV * NF / 4;   // 4,800,000
        int i = (b - 18) * 256 + threadIdx.x;
        if (i < n4) {
            f4 v = ((const f4*)lv)[i];
            u16x4 r;
            #pragma unroll
            for (int j = 0; j < 4; ++j) r[j] = f2bf(fmaxf(v[j], 0.f));
            ((u16x4*)xbf0)[i] = r;
        }
    }
}

// One lattice conv layer: out[n,o] = sum_k sum_f xin[nbr[n,k], f] * w[k][f][o] (+bias)
// LAYER==1: bfout = bf16(relu(conv + b))     (feeds next layer's gather)
// LAYER==2: fout  = conv + b + resid         (fp32 final output)
//
// All 9 tap-tiles are staged up front (18 global_load_lds per wave, all in
// flight); per-tap consume uses counted s_waitcnt vmcnt(16-2k) + RAW s_barrier
// (NOT __syncthreads, which would drain vmcnt to 0 and serialize the gather).
//
// Gather layout per tap: row-major LDS tile [64 rows][64 bf16] with XOR
// swizzle: LDS(r, c16) holds global 16B-chunk (c16 ^ (r&7)). Source is
// pre-swizzled so the LDS dest stays linear for global_load_lds; 8
// consecutive lanes cover one gathered row's 128B -> full line coalescing.
template<int LAYER>
__global__ __launch_bounds__(256, 2)
void conv_kernel(const unsigned short* __restrict__ xin,  // bf16 bits [NV][64]
                 const int* __restrict__ nbr,             // [NV][9]
                 const unsigned short* __restrict__ wt,   // bf16 [9][64][64], o-major
                 const float* __restrict__ bias,          // [64]
                 const float* __restrict__ resid,         // [NV][64] (LAYER==2)
                 unsigned short* __restrict__ bfout,      // LAYER==1
                 float* __restrict__ fout)                // LAYER==2
{
    __shared__ unsigned short gA[KT][64][64];  // 9 tap buffers, 8 KiB each = 73.7 KiB
    __shared__ int nbs[576];                   // 64 rows x 9 taps

    const int tid  = threadIdx.x;
    const int lane = tid & 63;
    const int wv   = tid >> 6;               // wave 0..3 -> output cols wv*16..+15
    const int base = blockIdx.x * 64;

    // neighbor tile -> LDS
    for (int e = tid; e < 576; e += 256) {
        long ge = (long)base * 9 + e;
        nbs[e] = (ge < (long)NV * 9) ? nbr[ge] : 0;
    }

    // all 18 B fragments in registers: lane l, reg j holds w[k][kk*32+(l>>4)*8+j][wv*16+(l&15)]
    const int bcol = wv * 16 + (lane & 15);
    const int bk   = (lane >> 4) * 8;
    bf16x8 bw[KT][2];
    #pragma unroll
    for (int k = 0; k < KT; ++k) {
        #pragma unroll
        for (int kk = 0; kk < 2; ++kk)
            bw[k][kk] = *(const bf16x8*)&wt[(k * 64 + bcol) * 64 + kk * 32 + bk];
    }

    f32x4 acc[4];
    #pragma unroll
    for (int im = 0; im < 4; ++im) acc[im] = (f32x4){0.f, 0.f, 0.f, 0.f};

    // drains vmcnt to 0 (bw + nbr loads) and publishes nbs — after this point
    // the ONLY vmem ops are the 18 stage loads below, so the counted vmcnt
    // ledger in the phase loop is exact.
    __syncthreads();

    // issue ALL tap stages now, tap-major (2 loads per tap per wave).
    // wave wv instruction h covers rows (wv+h*4)*8 .. +7; lane l: row
    // r = rblk*8 + (l>>3), fetches global chunk (l&7)^(r&7) into linear
    // LDS slot (r, l&7).
    const int sr_off = lane >> 3;
    const int sj     = lane & 7;
    #pragma unroll
    for (int k = 0; k < KT; ++k) {
        #pragma unroll
        for (int h = 0; h < 2; ++h) {
            const int rblk = wv + h * 4;     // 0..7
            const int r    = rblk * 8 + sr_off;
            const int nb   = nbs[r * 9 + k];
            const int gcol = sj ^ (r & 7);
            const unsigned short* src = xin + nb * 64 + gcol * 8;
            __builtin_amdgcn_global_load_lds(
                (const __attribute__((address_space(1))) unsigned int*)src,
                (__attribute__((address_space(3))) unsigned int*)&gA[k][rblk * 8][0],
                16, 0, 0);
        }
    }

    // per-tap compute (8 x ds_read_b128 + MFMA); compiler handles lgkmcnt
    auto tap = [&](int k) {
        #pragma unroll
        for (int im = 0; im < 4; ++im) {
            #pragma unroll
            for (int kk = 0; kk < 2; ++kk) {
                const int row = im * 16 + (lane & 15);
                const int c16 = kk * 4 + (lane >> 4);
                const int swc = c16 ^ (row & 7);
                bf16x8 a = *(const bf16x8*)&gA[k][row][swc * 8];
                acc[im] = __builtin_amdgcn_mfma_f32_16x16x32_bf16(a, bw[k][kk], acc[im], 0, 0, 0);
            }
        }
    };

    // counted waits: own tap-k loads retired at vmcnt(16-2k); raw barrier
    // rendezvous => ALL waves' tap-k loads landed. Later taps stay in flight.
    #define PHASE(K, VM)                                              \
        asm volatile("s_waitcnt vmcnt(" #VM ")" ::: "memory");        \
        __builtin_amdgcn_s_barrier();                                 \
        tap(K);
    PHASE(0, 16) PHASE(1, 14) PHASE(2, 12) PHASE(3, 10) PHASE(4, 8)
    PHASE(5, 6)  PHASE(6, 4)  PHASE(7, 2)  PHASE(8, 0)
    #undef PHASE

    // epilogue: D lane layout col = lane&15, row = (lane>>4)*4 + j  (within 16x16 tile)
    const int ocol = wv * 16 + (lane & 15);
    const int orow = (lane >> 4) * 4;
    const float bv = bias[ocol];
    #pragma unroll
    for (int im = 0; im < 4; ++im) {
        #pragma unroll
        for (int j = 0; j < 4; ++j) {
            const int r = base + im * 16 + orow + j;
            if (r < NV) {
                float v = acc[im][j] + bv;
                if (LAYER == 1) {
                    bfout[r * 64 + ocol] = f2bf(fmaxf(v, 0.f));
                } else {
                    fout[r * 64 + ocol] = v + resid[r * 64 + ocol];
                }
            }
        }
    }
}

extern "C" void kernel_launch(void* const* d_in, const int* in_sizes, int n_in,
                              void* d_out, int out_size, void* d_ws, size_t ws_size,
                              hipStream_t stream) {
    const float* lv  = (const float*)d_in[0];
    const int*   nbr = (const int*)d_in[1];
    const float* w1  = (const float*)d_in[2];
    const float* b1  = (const float*)d_in[3];
    const float* w2  = (const float*)d_in[4];
    const float* b2  = (const float*)d_in[5];
    float* out = (float*)d_out;

    // workspace layout (needs ~73.4 MiB)
    char* ws = (char*)d_ws;
    unsigned short* xbf0 = (unsigned short*)ws;                // 38,400,000 B: bf16 relu(lv)
    unsigned short* xbf1 = (unsigned short*)(ws + 38400000);   // 38,400,000 B: bf16 relu(y1)
    unsigned short* wt1  = (unsigned short*)(ws + 76800000);   // 73,728 B
    unsigned short* wt2  = (unsigned short*)(ws + 76873728);   // 73,728 B

    const int n4blk = (NV * NF / 4 + 255) / 256;               // 18750
    prep_kernel<<<18 + n4blk, 256, 0, stream>>>(lv, w1, w2, xbf0, wt1, wt2);
    conv_kernel<1><<<NBLK, 256, 0, stream>>>(xbf0, nbr, wt1, b1, nullptr, xbf1, nullptr);
    conv_kernel<2><<<NBLK, 256, 0, stream>>>(xbf1, nbr, wt2, b2, lv, nullptr, out);
}

// Round 6
// 316.415 us; speedup vs baseline: 1.1680x; 1.1680x over previous
//
#include <hip/hip_runtime.h>

#define NV 300000
#define KT 9
#define NF 64
#define NBLK ((NV + 63) / 64)   // 4688 blocks of 64 rows

typedef __attribute__((ext_vector_type(8))) short bf16x8;
typedef __attribute__((ext_vector_type(4))) float f32x4;
typedef __attribute__((ext_vector_type(4))) float f4;
typedef __attribute__((ext_vector_type(4))) unsigned short u16x4;

// round-to-nearest-even f32 -> bf16 bits
__device__ __forceinline__ unsigned short f2bf(float f) {
    union { float f; unsigned int u; } a; a.f = f;
    unsigned int u = a.u;
    return (unsigned short)((u + 0x7FFFu + ((u >> 16) & 1u)) >> 16);
}

// prep: blocks 0..17 transpose+cvt weights (w[k][f][o] -> wt[k][o][f] bf16),
//       blocks 18..  convert relu(lv) -> bf16 (exact grid, one f4/thread)
__global__ void prep_kernel(const float* __restrict__ lv,
                            const float* __restrict__ w1,
                            const float* __restrict__ w2,
                            unsigned short* __restrict__ xbf0,
                            unsigned short* __restrict__ wt1,
                            unsigned short* __restrict__ wt2) {
    int b = blockIdx.x;
    if (b < 18) {
        const float* w = (b < 9) ? w1 : w2;
        unsigned short* wt = (b < 9) ? wt1 : wt2;
        int k = (b < 9) ? b : b - 9;
        for (int e = threadIdx.x; e < NF * NF; e += 256) {
            int o = e >> 6, f = e & 63;
            wt[(k * NF + o) * NF + f] = f2bf(w[(k * NF + f) * NF + o]);
        }
    } else {
        const int n4 = NV * NF / 4;   // 4,800,000
        int i = (b - 18) * 256 + threadIdx.x;
        if (i < n4) {
            f4 v = ((const f4*)lv)[i];
            u16x4 r;
            #pragma unroll
            for (int j = 0; j < 4; ++j) r[j] = f2bf(fmaxf(v[j], 0.f));
            ((u16x4*)xbf0)[i] = r;
        }
    }
}

// One lattice conv layer: out[n,o] = sum_k sum_f xin[nbr[n,k], f] * w[k][f][o] (+bias)
// LAYER==1: bfout = bf16(relu(conv + b))     (feeds next layer's gather)
// LAYER==2: fout  = conv + b + resid         (fp32 final output)
//
// 4 rotating tap buffers (34.9 KB LDS -> 4 blocks/CU), depth-3 prefetch with
// counted s_waitcnt vmcnt + RAW s_barrier (never vmcnt(0) mid-loop). Steady
// state: 6 loads in flight/wave, ~96/CU.
//
// Gather layout per tap: row-major LDS tile [64 rows][64 bf16] with XOR
// swizzle: LDS(r, c16) holds global 16B-chunk (c16 ^ (r&7)). Source is
// pre-swizzled so the LDS dest stays linear for global_load_lds; 8
// consecutive lanes cover one gathered row's 128B -> full line coalescing.
template<int LAYER>
__global__ __launch_bounds__(256, 4)
void conv_kernel(const unsigned short* __restrict__ xin,  // bf16 bits [NV][64]
                 const int* __restrict__ nbr,             // [NV][9]
                 const unsigned short* __restrict__ wt,   // bf16 [9][64][64], o-major
                 const float* __restrict__ bias,          // [64]
                 const float* __restrict__ resid,         // [NV][64] (LAYER==2)
                 unsigned short* __restrict__ bfout,      // LAYER==1
                 float* __restrict__ fout)                // LAYER==2
{
    __shared__ unsigned short gA[4][64][64];  // 4 rotating tap buffers, 8 KiB each
    __shared__ int nbs[576];                  // 64 rows x 9 taps

    const int tid  = threadIdx.x;
    const int lane = tid & 63;
    const int wv   = tid >> 6;               // wave 0..3 -> output cols wv*16..+15
    const int base = blockIdx.x * 64;

    // neighbor tile -> LDS
    for (int e = tid; e < 576; e += 256) {
        long ge = (long)base * 9 + e;
        nbs[e] = (ge < (long)NV * 9) ? nbr[ge] : 0;
    }

    // all 18 B fragments in registers: lane l, reg j holds w[k][kk*32+(l>>4)*8+j][wv*16+(l&15)]
    const int bcol = wv * 16 + (lane & 15);
    const int bk   = (lane >> 4) * 8;
    bf16x8 bw[KT][2];
    #pragma unroll
    for (int k = 0; k < KT; ++k) {
        #pragma unroll
        for (int kk = 0; kk < 2; ++kk)
            bw[k][kk] = *(const bf16x8*)&wt[(k * 64 + bcol) * 64 + kk * 32 + bk];
    }

    f32x4 acc[4];
    #pragma unroll
    for (int im = 0; im < 4; ++im) acc[im] = (f32x4){0.f, 0.f, 0.f, 0.f};

    // drains vmcnt to 0 (bw + nbr loads) and publishes nbs — after this point
    // the ONLY vmem ops until the epilogue are the stage loads, so the counted
    // vmcnt ledger below is exact (asm "memory" clobbers keep bias/resid after).
    __syncthreads();

    // stage tap k into buffer k&3: wave wv instruction h covers rows
    // (wv+h*4)*8 .. +7; lane l: row r = rblk*8 + (l>>3), fetches global chunk
    // (l&7)^(r&7) into linear LDS slot (r, l&7).
    const int sr_off = lane >> 3;
    const int sj     = lane & 7;
    auto stage = [&](int k) {
        #pragma unroll
        for (int h = 0; h < 2; ++h) {
            const int rblk = wv + h * 4;     // 0..7
            const int r    = rblk * 8 + sr_off;
            const int nb   = nbs[r * 9 + k];
            const int gcol = sj ^ (r & 7);
            const unsigned short* src = xin + nb * 64 + gcol * 8;
            __builtin_amdgcn_global_load_lds(
                (const __attribute__((address_space(1))) unsigned int*)src,
                (__attribute__((address_space(3))) unsigned int*)&gA[k & 3][rblk * 8][0],
                16, 0, 0);
        }
    };

    // per-tap compute (8 x ds_read_b128 + MFMA); compiler handles lgkmcnt
    auto tap = [&](int k) {
        #pragma unroll
        for (int im = 0; im < 4; ++im) {
            #pragma unroll
            for (int kk = 0; kk < 2; ++kk) {
                const int row = im * 16 + (lane & 15);
                const int c16 = kk * 4 + (lane >> 4);
                const int swc = c16 ^ (row & 7);
                bf16x8 a = *(const bf16x8*)&gA[k & 3][row][swc * 8];
                acc[im] = __builtin_amdgcn_mfma_f32_16x16x32_bf16(a, bw[k][kk], acc[im], 0, 0, 0);
            }
        }
    };

    // depth-3 pipeline: prologue stages taps 0..2 (6 loads in flight).
    stage(0); stage(1); stage(2);

    // Phase k: vmcnt(N) retires own tap-k loads (N = loads of taps > k still
    // outstanding); s_barrier => ALL waves' tap-k loads landed AND all waves
    // finished tap k-1 (so buf (k+3)&3 == (k-1)&3 is free to restage).
    #define PHASE(K, VM, DO_STAGE)                                    \
        asm volatile("s_waitcnt vmcnt(" #VM ")" ::: "memory");        \
        __builtin_amdgcn_s_barrier();                                 \
        if (DO_STAGE) stage((K) + 3);                                 \
        tap(K);
    PHASE(0, 4, 1) PHASE(1, 4, 1) PHASE(2, 4, 1) PHASE(3, 4, 1)
    PHASE(4, 4, 1) PHASE(5, 4, 1) PHASE(6, 4, 0) PHASE(7, 2, 0)
    PHASE(8, 0, 0)
    #undef PHASE

    // epilogue: D lane layout col = lane&15, row = (lane>>4)*4 + j  (within 16x16 tile)
    const int ocol = wv * 16 + (lane & 15);
    const int orow = (lane >> 4) * 4;
    const float bv = bias[ocol];
    #pragma unroll
    for (int im = 0; im < 4; ++im) {
        #pragma unroll
        for (int j = 0; j < 4; ++j) {
            const int r = base + im * 16 + orow + j;
            if (r < NV) {
                float v = acc[im][j] + bv;
                if (LAYER == 1) {
                    bfout[r * 64 + ocol] = f2bf(fmaxf(v, 0.f));
                } else {
                    fout[r * 64 + ocol] = v + resid[r * 64 + ocol];
                }
            }
        }
    }
}

extern "C" void kernel_launch(void* const* d_in, const int* in_sizes, int n_in,
                              void* d_out, int out_size, void* d_ws, size_t ws_size,
                              hipStream_t stream) {
    const float* lv  = (const float*)d_in[0];
    const int*   nbr = (const int*)d_in[1];
    const float* w1  = (const float*)d_in[2];
    const float* b1  = (const float*)d_in[3];
    const float* w2  = (const float*)d_in[4];
    const float* b2  = (const float*)d_in[5];
    float* out = (float*)d_out;

    // workspace layout (needs ~73.4 MiB)
    char* ws = (char*)d_ws;
    unsigned short* xbf0 = (unsigned short*)ws;                // 38,400,000 B: bf16 relu(lv)
    unsigned short* xbf1 = (unsigned short*)(ws + 38400000);   // 38,400,000 B: bf16 relu(y1)
    unsigned short* wt1  = (unsigned short*)(ws + 76800000);   // 73,728 B
    unsigned short* wt2  = (unsigned short*)(ws + 76873728);   // 73,728 B

    const int n4blk = (NV * NF / 4 + 255) / 256;               // 18750
    prep_kernel<<<18 + n4blk, 256, 0, stream>>>(lv, w1, w2, xbf0, wt1, wt2);
    conv_kernel<1><<<NBLK, 256, 0, stream>>>(xbf0, nbr, wt1, b1, nullptr, xbf1, nullptr);
    conv_kernel<2><<<NBLK, 256, 0, stream>>>(xbf1, nbr, wt2, b2, lv, nullptr, out);
}

// Round 7
// 282.308 us; speedup vs baseline: 1.3091x; 1.1208x over previous
//
#include <hip/hip_runtime.h>

#define NV 300000
#define KT 9
#define NF 64
#define NBLK ((NV + 63) / 64)   // 4688 blocks of 64 rows

typedef __attribute__((ext_vector_type(8))) short bf16x8;
typedef __attribute__((ext_vector_type(4))) float f32x4;
typedef __attribute__((ext_vector_type(4))) float f4;
typedef __attribute__((ext_vector_type(4))) unsigned short u16x4;

// round-to-nearest-even f32 -> bf16 bits
__device__ __forceinline__ unsigned short f2bf(float f) {
    union { float f; unsigned int u; } a; a.f = f;
    unsigned int u = a.u;
    return (unsigned short)((u + 0x7FFFu + ((u >> 16) & 1u)) >> 16);
}

// prep: blocks 0..17 transpose+cvt weights (w[k][f][o] -> wt[k][o][f] bf16),
//       blocks 18..  convert relu(lv) -> bf16 (exact grid, one f4/thread)
__global__ void prep_kernel(const float* __restrict__ lv,
                            const float* __restrict__ w1,
                            const float* __restrict__ w2,
                            unsigned short* __restrict__ xbf0,
                            unsigned short* __restrict__ wt1,
                            unsigned short* __restrict__ wt2) {
    int b = blockIdx.x;
    if (b < 18) {
        const float* w = (b < 9) ? w1 : w2;
        unsigned short* wt = (b < 9) ? wt1 : wt2;
        int k = (b < 9) ? b : b - 9;
        for (int e = threadIdx.x; e < NF * NF; e += 256) {
            int o = e >> 6, f = e & 63;
            wt[(k * NF + o) * NF + f] = f2bf(w[(k * NF + f) * NF + o]);
        }
    } else {
        const int n4 = NV * NF / 4;   // 4,800,000
        int i = (b - 18) * 256 + threadIdx.x;
        if (i < n4) {
            f4 v = ((const f4*)lv)[i];
            u16x4 r;
            #pragma unroll
            for (int j = 0; j < 4; ++j) r[j] = f2bf(fmaxf(v[j], 0.f));
            ((u16x4*)xbf0)[i] = r;
        }
    }
}

// One lattice conv layer: out[n,o] = sum_k sum_f xin[nbr[n,k], f] * w[k][f][o] (+bias)
// LAYER==1: bfout = bf16(relu(conv + b))     (feeds next layer's gather)
// LAYER==2: fout  = conv + b + resid         (fp32 final output)
//
// High-TLP variant: 2 rotating tap buffers (18.7 KB LDS) -> 8 blocks/CU.
// Weights are NOT held across the loop (that forced the compiler to sink
// 72 VGPRs of loads unpredictably in R6); instead each phase's region
// explicitly issues {2 stage loads + 2 bw loads}, fenced, so the counted
// vmcnt(4) provably retires exactly region k. Two raw s_barriers per phase
// protect the 2-buffer rotation; vmcnt never drains to 0 mid-loop.
template<int LAYER>
__global__ __launch_bounds__(256, 8)
void conv_kernel(const unsigned short* __restrict__ xin,  // bf16 bits [NV][64]
                 const int* __restrict__ nbr,             // [NV][9]
                 const unsigned short* __restrict__ wt,   // bf16 [9][64][64], o-major
                 const float* __restrict__ bias,          // [64]
                 const float* __restrict__ resid,         // [NV][64] (LAYER==2)
                 unsigned short* __restrict__ bfout,      // LAYER==1
                 float* __restrict__ fout)                // LAYER==2
{
    __shared__ unsigned short gA[2][64][64];  // 2 rotating tap buffers, 8 KiB each
    __shared__ int nbs[576];                  // 64 rows x 9 taps

    const int tid  = threadIdx.x;
    const int lane = tid & 63;
    const int wv   = tid >> 6;               // wave 0..3 -> output cols wv*16..+15
    const int base = blockIdx.x * 64;

    // neighbor tile -> LDS
    for (int e = tid; e < 576; e += 256) {
        long ge = (long)base * 9 + e;
        nbs[e] = (ge < (long)NV * 9) ? nbr[ge] : 0;
    }

    const int bcol = wv * 16 + (lane & 15);
    const int bk   = (lane >> 4) * 8;
    // B-fragment load for tap k, half kk: lane l reg j = w[k][kk*32+(l>>4)*8+j][bcol]
    auto ldw = [&](int k, int kk) {
        return *(const bf16x8*)&wt[(k * 64 + bcol) * 64 + kk * 32 + bk];
    };

    f32x4 acc[4];
    #pragma unroll
    for (int im = 0; im < 4; ++im) acc[im] = (f32x4){0.f, 0.f, 0.f, 0.f};

    // drains vmcnt to 0 (nbr loads) and publishes nbs — after this the only
    // vmem ops until the epilogue are the fenced per-region {stage,bw} loads,
    // so the counted vmcnt ledger below is exact.
    __syncthreads();

    // stage tap k into buffer k&1: wave wv instruction h covers rows
    // (wv+h*4)*8 .. +7; lane l: row r = rblk*8 + (l>>3), fetches global chunk
    // (l&7)^(r&7) into linear LDS slot (r, l&7)  [both-sides XOR swizzle].
    const int sr_off = lane >> 3;
    const int sj     = lane & 7;
    auto stage = [&](int k) {
        #pragma unroll
        for (int h = 0; h < 2; ++h) {
            const int rblk = wv + h * 4;     // 0..7
            const int r    = rblk * 8 + sr_off;
            const int nb   = nbs[r * 9 + k];
            const int gcol = sj ^ (r & 7);
            const unsigned short* src = xin + nb * 64 + gcol * 8;
            __builtin_amdgcn_global_load_lds(
                (const __attribute__((address_space(1))) unsigned int*)src,
                (__attribute__((address_space(3))) unsigned int*)&gA[k & 1][rblk * 8][0],
                16, 0, 0);
        }
    };

    // per-tap compute: 8 x ds_read_b128 (XOR-swizzled, conflict-free) + MFMA
    auto tap = [&](int k, bf16x8 (&bwk)[2]) {
        #pragma unroll
        for (int im = 0; im < 4; ++im) {
            #pragma unroll
            for (int kk = 0; kk < 2; ++kk) {
                const int row = im * 16 + (lane & 15);
                const int c16 = kk * 4 + (lane >> 4);
                const int swc = c16 ^ (row & 7);
                bf16x8 a = *(const bf16x8*)&gA[k & 1][row][swc * 8];
                acc[im] = __builtin_amdgcn_mfma_f32_16x16x32_bf16(a, bwk[kk], acc[im], 0, 0, 0);
            }
        }
    };

    #define FENCE asm volatile("" ::: "memory")

    bf16x8 bwreg[2][2];   // [tap&1][kk] — all indices compile-time constants

    // prologue: region 0 = {bw(0), stage(0)}, region 1 = {bw(1), stage(1)}
    bwreg[0][0] = ldw(0, 0); bwreg[0][1] = ldw(0, 1); stage(0); FENCE;
    bwreg[1][0] = ldw(1, 0); bwreg[1][1] = ldw(1, 1); stage(1); FENCE;

    // Phase K: vmcnt(4) retires region K (its 4 ops are the oldest; region
    // K+1's 4 ops remain). barrier#1: all waves' tap-K data landed.
    // tap(K). barrier#2: all waves done reading buf K&1 -> safe to restage.
    // Region K+2 = {stage(K+2), bw(K+2)} into buf/reg slot K&1.
    #define PHASE(K, VM)                                                   \
        asm volatile("s_waitcnt vmcnt(" #VM ")" ::: "memory");             \
        __builtin_amdgcn_s_barrier();                                      \
        tap(K, bwreg[(K) & 1]);                                            \
        FENCE;                                                             \
        __builtin_amdgcn_s_barrier();                                      \
        if ((K) + 2 <= 8) {                                                \
            stage((K) + 2);                                                \
            bwreg[(K) & 1][0] = ldw((K) + 2, 0);                           \
            bwreg[(K) & 1][1] = ldw((K) + 2, 1);                           \
        }                                                                  \
        FENCE;
    PHASE(0, 4) PHASE(1, 4) PHASE(2, 4) PHASE(3, 4) PHASE(4, 4)
    PHASE(5, 4) PHASE(6, 4) PHASE(7, 4) PHASE(8, 0)
    #undef PHASE
    #undef FENCE

    // epilogue: D lane layout col = lane&15, row = (lane>>4)*4 + j  (within 16x16 tile)
    const int ocol = wv * 16 + (lane & 15);
    const int orow = (lane >> 4) * 4;
    const float bv = bias[ocol];
    #pragma unroll
    for (int im = 0; im < 4; ++im) {
        #pragma unroll
        for (int j = 0; j < 4; ++j) {
            const int r = base + im * 16 + orow + j;
            if (r < NV) {
                float v = acc[im][j] + bv;
                if (LAYER == 1) {
                    bfout[r * 64 + ocol] = f2bf(fmaxf(v, 0.f));
                } else {
                    fout[r * 64 + ocol] = v + resid[r * 64 + ocol];
                }
            }
        }
    }
}

extern "C" void kernel_launch(void* const* d_in, const int* in_sizes, int n_in,
                              void* d_out, int out_size, void* d_ws, size_t ws_size,
                              hipStream_t stream) {
    const float* lv  = (const float*)d_in[0];
    const int*   nbr = (const int*)d_in[1];
    const float* w1  = (const float*)d_in[2];
    const float* b1  = (const float*)d_in[3];
    const float* w2  = (const float*)d_in[4];
    const float* b2  = (const float*)d_in[5];
    float* out = (float*)d_out;

    // workspace layout (needs ~73.4 MiB)
    char* ws = (char*)d_ws;
    unsigned short* xbf0 = (unsigned short*)ws;                // 38,400,000 B: bf16 relu(lv)
    unsigned short* xbf1 = (unsigned short*)(ws + 38400000);   // 38,400,000 B: bf16 relu(y1)
    unsigned short* wt1  = (unsigned short*)(ws + 76800000);   // 73,728 B
    unsigned short* wt2  = (unsigned short*)(ws + 76873728);   // 73,728 B

    const int n4blk = (NV * NF / 4 + 255) / 256;               // 18750
    prep_kernel<<<18 + n4blk, 256, 0, stream>>>(lv, w1, w2, xbf0, wt1, wt2);
    conv_kernel<1><<<NBLK, 256, 0, stream>>>(xbf0, nbr, wt1, b1, nullptr, xbf1, nullptr);
    conv_kernel<2><<<NBLK, 256, 0, stream>>>(xbf1, nbr, wt2, b2, lv, nullptr, out);
}